// Round 4
// baseline (263.131 us; speedup 1.0000x reference)
//
#include <hip/hip_runtime.h>
#include <hip/hip_bf16.h>

#define BATCH 8
#define CCH 1024
#define NHW 4096
#define SCALE 5.0f   // 1/TEMPERATURE
#define ROWS (BATCH * CCH)

typedef unsigned short u16;
typedef __attribute__((ext_vector_type(8))) short short8;
typedef __attribute__((ext_vector_type(4))) float float4v;

__device__ __forceinline__ void async_load16(const void* gsrc, void* ldst) {
    __builtin_amdgcn_global_load_lds(
        (__attribute__((address_space(1))) void*)gsrc,
        (__attribute__((address_space(3))) void*)ldst,
        16, 0, 0);
}

__device__ __forceinline__ u16 f2bf(float f) {
    union { float f; unsigned int u; } c; c.f = f;
    unsigned int u = c.u;
    unsigned int r = u + 0x7FFFu + ((u >> 16) & 1u);
    return (u16)(r >> 16);
}

// One block per row: diag = sum(x^2)*SCALE, zero l_acc, optionally convert to bf16.
template <bool CONVERT>
__global__ __launch_bounds__(256) void prep_kernel(const float* __restrict__ x,
                                                   u16* __restrict__ xbf,
                                                   float* __restrict__ diag,
                                                   float* __restrict__ l_acc) {
    const int row = blockIdx.x;          // 0..8191
    const int tid = threadIdx.x;
    const float* src = x + (size_t)row * NHW;
    float ssum = 0.f;
#pragma unroll
    for (int p = 0; p < 4; ++p) {
        const int idx = p * 1024 + tid * 4;
        float4 v = *(const float4*)(src + idx);
        ssum += v.x * v.x + v.y * v.y + v.z * v.z + v.w * v.w;
        if (CONVERT) {
            ushort4 o;
            o.x = f2bf(v.x); o.y = f2bf(v.y); o.z = f2bf(v.z); o.w = f2bf(v.w);
            *(ushort4*)(xbf + (size_t)row * NHW + idx) = o;
        }
    }
#pragma unroll
    for (int m = 1; m < 64; m <<= 1) ssum += __shfl_xor(ssum, m);
    __shared__ float red[4];
    if ((tid & 63) == 0) red[tid >> 6] = ssum;
    __syncthreads();
    if (tid == 0) {
        diag[row] = (red[0] + red[1] + red[2] + red[3]) * SCALE;
        l_acc[row] = 0.f;
    }
}

// Symmetric Gram, 64x64 tiles over the upper triangle (bj >= bi), BK=128.
// Grid = 8 batches * 136 tiles = 1088 blocks (4.25 blocks/CU).
// LDS: row stride = 256B = 16 chunks of 16B; chunk (r, kc) at slot kc^(r&15).
// -> DMA staging coalesced (4 rows x permuted 256B span per instr) AND
//    fragment ds_read_b128 only 2-way bank-aliased (free).
// Diagonal tiles (bi==bj) stage A only; B fragments alias As.
template <bool BF16SRC>
__global__ __launch_bounds__(256) void gram_kernel(const u16* __restrict__ Xbf,
                                                   const float* __restrict__ Xf,
                                                   const float* __restrict__ diag,
                                                   float* __restrict__ l_acc,
                                                   float* __restrict__ num) {
    __shared__ __align__(16) u16 As[8192];   // 64 rows * 128 u16 = 16KB
    __shared__ __align__(16) u16 Bs[8192];   // 64 rows * 128 u16 = 16KB

    const int bid = blockIdx.x;
    const int b = bid & 7;           // batch in low bits -> XCD spread
    const int t = bid >> 3;          // 0..135 upper-tile index

    int bi = 0;
#pragma unroll
    for (int i = 15; i >= 1; --i) {  // off(i) = i*16 - i*(i-1)/2
        if (t >= i * 16 - (i * (i - 1)) / 2) { bi = i; break; }
    }
    const int bj = bi + (t - (bi * 16 - (bi * (bi - 1)) / 2));  // 0..15
    const bool diagtile = (bi == bj);

    const int tid  = threadIdx.x;
    const int lane = tid & 63;
    const int w    = tid >> 6;       // wave 0..3
    const int wm   = w >> 1;         // wave row-half 0..1 (32 rows)
    const int wn   = w & 1;          // wave col-half 0..1 (32 cols)

    // Staging lane mapping (per instr = 4 rows x 16 slots):
    // lane l: row_local = l>>4, dest slot = l&15,
    // source kchunk = (l&15) ^ (l>>4) ^ (t4*4)  [t4 = 4-row group index]
    const int st_r4 = lane >> 4;               // 0..3
    const int st_k0 = (lane & 15) ^ st_r4;     // base source kchunk (t4=0)

    const u16*   pA  = nullptr; const u16*   pB  = nullptr;
    const float* pAf = nullptr; const float* pBf = nullptr;
    if (BF16SRC) {
        const u16* baseX = Xbf + (size_t)b * CCH * NHW;
        pA = baseX + (size_t)(bi * 64 + w * 16 + st_r4) * NHW;
        pB = baseX + (size_t)(bj * 64 + w * 16 + st_r4) * NHW;
    } else {
        const float* baseXf = Xf + (size_t)b * CCH * NHW;
        pAf = baseXf + (size_t)(bi * 64 + w * 16 + st_r4) * NHW;
        pBf = baseXf + (size_t)(bj * 64 + w * 16 + st_r4) * NHW;
    }

    float4v acc[2][2] = {};

    for (int K0 = 0; K0 < NHW; K0 += 128) {
        __syncthreads();   // previous iter's LDS reads complete
        if (BF16SRC) {
#pragma unroll
            for (int t4 = 0; t4 < 4; ++t4) {
                const int kc = st_k0 ^ (t4 * 4);
                async_load16(pA + (size_t)(t4 * 4) * NHW + K0 + kc * 8,
                             As + (size_t)(w * 16 + t4 * 4) * 128);
            }
            if (!diagtile) {
#pragma unroll
                for (int t4 = 0; t4 < 4; ++t4) {
                    const int kc = st_k0 ^ (t4 * 4);
                    async_load16(pB + (size_t)(t4 * 4) * NHW + K0 + kc * 8,
                                 Bs + (size_t)(w * 16 + t4 * 4) * 128);
                }
            }
        } else {
#pragma unroll
            for (int t4 = 0; t4 < 4; ++t4) {
                const int kc = st_k0 ^ (t4 * 4);
                const float* s = pAf + (size_t)(t4 * 4) * NHW + K0 + kc * 8;
                float4 f0 = *(const float4*)(s);
                float4 f1 = *(const float4*)(s + 4);
                u16* d = As + (size_t)(w * 16 + t4 * 4 + st_r4) * 128 + (lane & 15) * 8;
                d[0]=f2bf(f0.x); d[1]=f2bf(f0.y); d[2]=f2bf(f0.z); d[3]=f2bf(f0.w);
                d[4]=f2bf(f1.x); d[5]=f2bf(f1.y); d[6]=f2bf(f1.z); d[7]=f2bf(f1.w);
            }
            if (!diagtile) {
#pragma unroll
                for (int t4 = 0; t4 < 4; ++t4) {
                    const int kc = st_k0 ^ (t4 * 4);
                    const float* s = pBf + (size_t)(t4 * 4) * NHW + K0 + kc * 8;
                    float4 f0 = *(const float4*)(s);
                    float4 f1 = *(const float4*)(s + 4);
                    u16* d = Bs + (size_t)(w * 16 + t4 * 4 + st_r4) * 128 + (lane & 15) * 8;
                    d[0]=f2bf(f0.x); d[1]=f2bf(f0.y); d[2]=f2bf(f0.z); d[3]=f2bf(f0.w);
                    d[4]=f2bf(f1.x); d[5]=f2bf(f1.y); d[6]=f2bf(f1.z); d[7]=f2bf(f1.w);
                }
            }
        }
        __syncthreads();   // staging visible (vmcnt drained before barrier)

        const u16* Bbase = diagtile ? As : Bs;
#pragma unroll
        for (int ks = 0; ks < 4; ++ks) {
            short8 af[2], bf[2];
            const int q  = lane >> 4;          // 0..3
            const int rl = lane & 15;
            const int kq = ks * 4 + q;         // kchunk 0..15
            const int slot = kq ^ rl;          // swizzled slot
#pragma unroll
            for (int mt = 0; mt < 2; ++mt)
                af[mt] = *(const short8*)(As + (size_t)(wm * 32 + mt * 16 + rl) * 128 + slot * 8);
#pragma unroll
            for (int nt = 0; nt < 2; ++nt)
                bf[nt] = *(const short8*)(Bbase + (size_t)(wn * 32 + nt * 16 + rl) * 128 + slot * 8);
#pragma unroll
            for (int mt = 0; mt < 2; ++mt)
#pragma unroll
                for (int nt = 0; nt < 2; ++nt)
                    acc[mt][nt] = __builtin_amdgcn_mfma_f32_16x16x32_bf16(af[mt], bf[nt], acc[mt][nt], 0, 0, 0);
        }
    }

    // ---- Epilogue ----
    const int q  = lane >> 4;    // row-quad 0..3
    const int cl = lane & 15;    // col within 16
    const int rowbase = bi * 64 + wm * 32;
    const int colbase = bj * 64 + wn * 32;
    const float* dgb = diag + b * CCH;
    float* lb = l_acc + b * CCH;

    // Row sums (upper-inclusive) + diagonal numerator
#pragma unroll
    for (int mt = 0; mt < 2; ++mt) {
#pragma unroll
        for (int reg = 0; reg < 4; ++reg) {
            const int gr = rowbase + mt * 16 + q * 4 + reg;
            const float dg = dgb[gr];
            float s = 0.f;
#pragma unroll
            for (int nt = 0; nt < 2; ++nt) {
                const int gc = colbase + nt * 16 + cl;
                const float e = __expf(acc[mt][nt][reg] * SCALE - dg);
                if (gr <= gc) s += e;
                if (gr == gc) num[b * CCH + gr] = e;
            }
            s += __shfl_xor(s, 1);
            s += __shfl_xor(s, 2);
            s += __shfl_xor(s, 4);
            s += __shfl_xor(s, 8);
            if (cl == 0) atomicAdd(lb + gr, s);
        }
    }

    // Column sums (strictly-upper -> transposed contribution)
#pragma unroll
    for (int nt = 0; nt < 2; ++nt) {
        const int gc = colbase + nt * 16 + cl;
        const float dgc = dgb[gc];
        float s = 0.f;
#pragma unroll
        for (int mt = 0; mt < 2; ++mt) {
#pragma unroll
            for (int reg = 0; reg < 4; ++reg) {
                const int gr = rowbase + mt * 16 + q * 4 + reg;
                if (gr < gc) s += __expf(acc[mt][nt][reg] * SCALE - dgc);
            }
        }
        s += __shfl_xor(s, 16);
        s += __shfl_xor(s, 32);
        if (lane < 16) atomicAdd(lb + gc, s);
    }
}

__global__ __launch_bounds__(1024) void finalize_kernel(const float* __restrict__ l_acc,
                                                        const float* __restrict__ num,
                                                        float* __restrict__ out) {
    const int tid = threadIdx.x;
    float s = 0.f;
    for (int r = tid; r < ROWS; r += 1024) {
        const float d = num[r] / l_acc[r];
        s += -__logf(d + 1e-10f);
    }
#pragma unroll
    for (int m = 1; m < 64; m <<= 1) s += __shfl_xor(s, m);
    __shared__ float red[16];
    if ((tid & 63) == 0) red[tid >> 6] = s;
    __syncthreads();
    if (tid == 0) {
        float tot = 0.f;
#pragma unroll
        for (int i = 0; i < 16; ++i) tot += red[i];
        out[0] = tot * (1.0f / (float)ROWS);
    }
}

extern "C" void kernel_launch(void* const* d_in, const int* in_sizes, int n_in,
                              void* d_out, int out_size, void* d_ws, size_t ws_size,
                              hipStream_t stream) {
    const float* x = (const float*)d_in[0];
    float* out = (float*)d_out;

    const size_t xbf_bytes  = (size_t)BATCH * CCH * NHW * 2;  // 67108864
    const size_t stat_bytes = (size_t)ROWS * 4;               // 32768
    const bool fast = ws_size >= xbf_bytes + 3 * stat_bytes;

    const int ntiles = 136;  // 16*17/2 upper-triangle 64x64 tiles per batch

    if (fast) {
        u16*   xbf   = (u16*)d_ws;
        float* diag  = (float*)((char*)d_ws + xbf_bytes);
        float* l_acc = diag + ROWS;
        float* num   = l_acc + ROWS;
        prep_kernel<true><<<ROWS, 256, 0, stream>>>(x, xbf, diag, l_acc);
        gram_kernel<true><<<BATCH * ntiles, 256, 0, stream>>>(xbf, nullptr, diag, l_acc, num);
        finalize_kernel<<<1, 1024, 0, stream>>>(l_acc, num, out);
    } else {
        float* diag  = (float*)d_ws;
        float* l_acc = diag + ROWS;
        float* num   = l_acc + ROWS;
        prep_kernel<false><<<ROWS, 256, 0, stream>>>(x, nullptr, diag, l_acc);
        gram_kernel<false><<<BATCH * ntiles, 256, 0, stream>>>(nullptr, x, diag, l_acc, num);
        finalize_kernel<<<1, 1024, 0, stream>>>(l_acc, num, out);
    }
}

// Round 5
// 243.126 us; speedup vs baseline: 1.0823x; 1.0823x over previous
//
#include <hip/hip_runtime.h>
#include <hip/hip_bf16.h>

#define BATCH 8
#define CCH 1024
#define NHW 4096
#define SCALE 5.0f   // 1/TEMPERATURE
#define ROWS (BATCH * CCH)

typedef unsigned char u8;
typedef unsigned int u32;
typedef __attribute__((ext_vector_type(4))) float float4v;

__device__ __forceinline__ void async_load16(const void* gsrc, void* ldst) {
    __builtin_amdgcn_global_load_lds(
        (__attribute__((address_space(1))) void*)gsrc,
        (__attribute__((address_space(3))) void*)ldst,
        16, 0, 0);
}

// pack 4 floats -> 4 OCP e4m3 bytes
__device__ __forceinline__ u32 pk4_fp8(float a, float b, float c, float d) {
    u32 v = __builtin_amdgcn_cvt_pk_fp8_f32(a, b, 0, false);
    v = __builtin_amdgcn_cvt_pk_fp8_f32(c, d, v, true);
    return v;
}

// sum of squares of the 4 fp8 values packed in q (dequantized)
__device__ __forceinline__ float ssq4_fp8(u32 q) {
    float d0 = __builtin_amdgcn_cvt_f32_fp8(q, 0);
    float d1 = __builtin_amdgcn_cvt_f32_fp8(q, 1);
    float d2 = __builtin_amdgcn_cvt_f32_fp8(q, 2);
    float d3 = __builtin_amdgcn_cvt_f32_fp8(q, 3);
    return d0 * d0 + d1 * d1 + d2 * d2 + d3 * d3;
}

// One block per row: quantize x -> fp8 (ws path), diag = 5*sum(q(x)^2) computed
// from the QUANTIZED values (so the MFMA diagonal dot cancels exactly), zero l_acc.
template <bool CONVERT>
__global__ __launch_bounds__(256) void prep_kernel(const float* __restrict__ x,
                                                   u8* __restrict__ xq,
                                                   float* __restrict__ diag,
                                                   float* __restrict__ l_acc) {
    const int row = blockIdx.x;          // 0..8191
    const int tid = threadIdx.x;
    const float* src = x + (size_t)row * NHW;
    float ssum = 0.f;
#pragma unroll
    for (int p = 0; p < 4; ++p) {
        const int idx = p * 1024 + tid * 4;
        float4 v = *(const float4*)(src + idx);
        const u32 q = pk4_fp8(v.x, v.y, v.z, v.w);
        ssum += ssq4_fp8(q);             // diag from quantized values (both paths)
        if (CONVERT) *(u32*)(xq + (size_t)row * NHW + idx) = q;
    }
#pragma unroll
    for (int m = 1; m < 64; m <<= 1) ssum += __shfl_xor(ssum, m);
    __shared__ float red[4];
    if ((tid & 63) == 0) red[tid >> 6] = ssum;
    __syncthreads();
    if (tid == 0) {
        diag[row] = (red[0] + red[1] + red[2] + red[3]) * SCALE;
        l_acc[row] = 0.f;
    }
}

// Symmetric Gram, fp8 e4m3, 128x64 tiles over upper triangle (bj2 >= 2*bi),
// BK=128 (bytes == elements). Grid = 8 batches * 72 tiles = 576 blocks.
// One fp8 batch slice = 4 MB = one XCD L2; b = bid&7 pins batch->XCD.
// LDS: row = 128 B = 8 chunks of 16 B; chunk (r, kc) at slot kc ^ (r&7)
// -> DMA coalesced (8 rows x permuted 128 B span / instr), frag reads ~2-way.
// Tiles with bj2 in {2bi, 2bi+1}: B rows are a subset of A rows -> alias As.
template <bool QSRC>
__global__ __launch_bounds__(256) void gram_kernel(const u8* __restrict__ Xq,
                                                   const float* __restrict__ Xf,
                                                   const float* __restrict__ diag,
                                                   float* __restrict__ l_acc,
                                                   float* __restrict__ num) {
    __shared__ __align__(16) u8 As[16384];   // 128 rows * 128 B
    __shared__ __align__(16) u8 Bs[8192];    //  64 rows * 128 B

    const int bid = blockIdx.x;
    const int b = bid & 7;           // batch -> XCD (heuristic)
    const int t = bid >> 3;          // 0..71 upper-tile index

    int bi = 0;
#pragma unroll
    for (int i = 7; i >= 1; --i) {   // off(bi) = bi*(17-bi), increasing
        if (t >= i * (17 - i)) { bi = i; break; }
    }
    const int bj2 = 2 * bi + (t - bi * (17 - bi));   // 64-col block, 0..15
    const bool aliasB = (bj2 == 2 * bi) || (bj2 == 2 * bi + 1);

    const int tid  = threadIdx.x;
    const int lane = tid & 63;
    const int w    = tid >> 6;       // wave 0..3
    const int wm   = w >> 1;         // wave row-half (64 rows)
    const int wn   = w & 1;          // wave col-half (32 cols)

    // Staging: instr covers 8 rows x 8 slots. lane l -> row l>>3, slot l&7,
    // source kchunk = (l&7) ^ (l>>3).
    const int st_r  = lane >> 3;               // 0..7
    const int st_kc = (lane & 7) ^ st_r;       // source 16B-chunk

    const u8*    pA  = nullptr; const u8*    pB  = nullptr;
    const float* pAf = nullptr; const float* pBf = nullptr;
    if (QSRC) {
        const u8* baseX = Xq + (size_t)b * CCH * NHW;
        pA = baseX + (size_t)(bi * 128 + w * 32 + st_r) * NHW + st_kc * 16;
        pB = baseX + (size_t)(bj2 * 64 + w * 16 + st_r) * NHW + st_kc * 16;
    } else {
        const float* baseXf = Xf + (size_t)b * CCH * NHW;
        pAf = baseXf + (size_t)(bi * 128 + w * 32 + st_r) * NHW + st_kc * 16;
        pBf = baseXf + (size_t)(bj2 * 64 + w * 16 + st_r) * NHW + st_kc * 16;
    }

    float4v acc[4][2] = {};

    for (int K0 = 0; K0 < NHW; K0 += 128) {
        __syncthreads();   // previous iter's LDS reads complete
        if (QSRC) {
#pragma unroll
            for (int t8 = 0; t8 < 4; ++t8)     // A: 32 rows per wave
                async_load16(pA + (size_t)(t8 * 8) * NHW + K0,
                             As + (size_t)(w * 32 + t8 * 8) * 128);
            if (!aliasB) {
#pragma unroll
                for (int t8 = 0; t8 < 2; ++t8) // B: 16 rows per wave
                    async_load16(pB + (size_t)(t8 * 8) * NHW + K0,
                                 Bs + (size_t)(w * 16 + t8 * 8) * 128);
            }
        } else {
#pragma unroll
            for (int t8 = 0; t8 < 4; ++t8) {
                const float* s = pAf + (size_t)(t8 * 8) * NHW + K0;
                float4 f0 = *(const float4*)(s);
                float4 f1 = *(const float4*)(s + 4);
                float4 f2 = *(const float4*)(s + 8);
                float4 f3 = *(const float4*)(s + 12);
                u32* d = (u32*)(As + (size_t)(w * 32 + t8 * 8 + st_r) * 128 + (lane & 7) * 16);
                d[0] = pk4_fp8(f0.x, f0.y, f0.z, f0.w);
                d[1] = pk4_fp8(f1.x, f1.y, f1.z, f1.w);
                d[2] = pk4_fp8(f2.x, f2.y, f2.z, f2.w);
                d[3] = pk4_fp8(f3.x, f3.y, f3.z, f3.w);
            }
            if (!aliasB) {
#pragma unroll
                for (int t8 = 0; t8 < 2; ++t8) {
                    const float* s = pBf + (size_t)(t8 * 8) * NHW + K0;
                    float4 f0 = *(const float4*)(s);
                    float4 f1 = *(const float4*)(s + 4);
                    float4 f2 = *(const float4*)(s + 8);
                    float4 f3 = *(const float4*)(s + 12);
                    u32* d = (u32*)(Bs + (size_t)(w * 16 + t8 * 8 + st_r) * 128 + (lane & 7) * 16);
                    d[0] = pk4_fp8(f0.x, f0.y, f0.z, f0.w);
                    d[1] = pk4_fp8(f1.x, f1.y, f1.z, f1.w);
                    d[2] = pk4_fp8(f2.x, f2.y, f2.z, f2.w);
                    d[3] = pk4_fp8(f3.x, f3.y, f3.z, f3.w);
                }
            }
        }
        __syncthreads();   // staging visible

        const u8* Bbase = aliasB ? (As + (size_t)(bj2 - 2 * bi) * 64 * 128) : Bs;
        const int q  = lane >> 4;
        const int rl = lane & 15;
#pragma unroll
        for (int s = 0; s < 4; ++s) {          // 4 k-steps of 32
            const int cbase = 2 * s + (q >> 1);    // 16B chunk index
            const int off8  = (q & 1) * 8;
            long af[4], bf[2];
#pragma unroll
            for (int mt = 0; mt < 4; ++mt)
                af[mt] = *(const long*)(As + (size_t)(wm * 64 + mt * 16 + rl) * 128
                                           + (size_t)(cbase ^ (rl & 7)) * 16 + off8);
#pragma unroll
            for (int nt = 0; nt < 2; ++nt)
                bf[nt] = *(const long*)(Bbase + (size_t)(wn * 32 + nt * 16 + rl) * 128
                                              + (size_t)(cbase ^ (rl & 7)) * 16 + off8);
#pragma unroll
            for (int mt = 0; mt < 4; ++mt)
#pragma unroll
                for (int nt = 0; nt < 2; ++nt)
                    acc[mt][nt] = __builtin_amdgcn_mfma_f32_16x16x32_fp8_fp8(af[mt], bf[nt], acc[mt][nt], 0, 0, 0);
        }
    }

    // ---- Epilogue ----
    const int q  = lane >> 4;    // row-quad 0..3
    const int cl = lane & 15;    // col within 16
    const int rowbase = bi * 128 + wm * 64;
    const int colbase = bj2 * 64 + wn * 32;
    const float* dgb = diag + b * CCH;
    float* lb = l_acc + b * CCH;

    // Row sums (upper-inclusive) + diagonal numerator
#pragma unroll
    for (int mt = 0; mt < 4; ++mt) {
#pragma unroll
        for (int reg = 0; reg < 4; ++reg) {
            const int gr = rowbase + mt * 16 + q * 4 + reg;
            const float dg = dgb[gr];
            float s = 0.f;
#pragma unroll
            for (int nt = 0; nt < 2; ++nt) {
                const int gc = colbase + nt * 16 + cl;
                const float e = __expf(acc[mt][nt][reg] * SCALE - dg);
                if (gr <= gc) s += e;
                if (gr == gc) num[b * CCH + gr] = e;
            }
            s += __shfl_xor(s, 1);
            s += __shfl_xor(s, 2);
            s += __shfl_xor(s, 4);
            s += __shfl_xor(s, 8);
            if (cl == 0) atomicAdd(lb + gr, s);
        }
    }

    // Column sums (strictly-upper -> transposed contribution)
#pragma unroll
    for (int nt = 0; nt < 2; ++nt) {
        const int gc = colbase + nt * 16 + cl;
        const float dgc = dgb[gc];
        float s = 0.f;
#pragma unroll
        for (int mt = 0; mt < 4; ++mt) {
#pragma unroll
            for (int reg = 0; reg < 4; ++reg) {
                const int gr = rowbase + mt * 16 + q * 4 + reg;
                if (gr < gc) s += __expf(acc[mt][nt][reg] * SCALE - dgc);
            }
        }
        s += __shfl_xor(s, 16);
        s += __shfl_xor(s, 32);
        if (lane < 16) atomicAdd(lb + gc, s);
    }
}

__global__ __launch_bounds__(1024) void finalize_kernel(const float* __restrict__ l_acc,
                                                        const float* __restrict__ num,
                                                        float* __restrict__ out) {
    const int tid = threadIdx.x;
    float s = 0.f;
    for (int r = tid; r < ROWS; r += 1024) {
        const float d = num[r] / l_acc[r];
        s += -__logf(d + 1e-10f);
    }
#pragma unroll
    for (int m = 1; m < 64; m <<= 1) s += __shfl_xor(s, m);
    __shared__ float red[16];
    if ((tid & 63) == 0) red[tid >> 6] = s;
    __syncthreads();
    if (tid == 0) {
        float tot = 0.f;
#pragma unroll
        for (int i = 0; i < 16; ++i) tot += red[i];
        out[0] = tot * (1.0f / (float)ROWS);
    }
}

extern "C" void kernel_launch(void* const* d_in, const int* in_sizes, int n_in,
                              void* d_out, int out_size, void* d_ws, size_t ws_size,
                              hipStream_t stream) {
    const float* x = (const float*)d_in[0];
    float* out = (float*)d_out;

    const size_t xq_bytes   = (size_t)BATCH * CCH * NHW;      // 33554432 (fp8)
    const size_t stat_bytes = (size_t)ROWS * 4;               // 32768
    const bool fast = ws_size >= xq_bytes + 3 * stat_bytes;

    const int ntiles = 72;  // 128x64 upper-triangle tiles per batch

    if (fast) {
        u8*    xq    = (u8*)d_ws;
        float* diag  = (float*)((char*)d_ws + xq_bytes);
        float* l_acc = diag + ROWS;
        float* num   = l_acc + ROWS;
        prep_kernel<true><<<ROWS, 256, 0, stream>>>(x, xq, diag, l_acc);
        gram_kernel<true><<<BATCH * ntiles, 256, 0, stream>>>(xq, nullptr, diag, l_acc, num);
        finalize_kernel<<<1, 1024, 0, stream>>>(l_acc, num, out);
    } else {
        float* diag  = (float*)d_ws;
        float* l_acc = diag + ROWS;
        float* num   = l_acc + ROWS;
        prep_kernel<false><<<ROWS, 256, 0, stream>>>(x, nullptr, diag, l_acc);
        gram_kernel<false><<<BATCH * ntiles, 256, 0, stream>>>(nullptr, x, diag, l_acc, num);
        finalize_kernel<<<1, 1024, 0, stream>>>(l_acc, num, out);
    }
}